// Round 1
// 1389.490 us; speedup vs baseline: 1.0008x; 1.0008x over previous
//
#include <hip/hip_runtime.h>
#include <hip/hip_bf16.h>
#include <math.h>

typedef __hip_bfloat16 bf16;

#define DINL __device__ __forceinline__
DINL float b2f(bf16 x){ return __bfloat162float(x); }
DINL bf16 f2b(float x){ return __float2bfloat16(x); }

DINL float ldin(const void* p, size_t i, int isb){
    return isb ? b2f(((const bf16*)p)[i]) : ((const float*)p)[i];
}
DINL void stout(void* p, size_t i, float v, int isb){
    if(isb) ((bf16*)p)[i] = f2b(v); else ((float*)p)[i] = v;
}

static constexpr int NRES = 512;
static constexpr int CS   = 384;
static constexpr int CZ   = 128;
static constexpr int NH   = 12;
static constexpr int PQn  = 4;
static constexpr int CAT  = 2112;
static constexpr int ASTR = 516;   // a_sf row stride (fp32): conflict-free (measured r5)
static constexpr int ZSTR = 136;   // zn_s row stride (bf16): 272B rows, 16B-aligned
static constexpr int SAK  = 56;    // GEMM LDS stride
static constexpr int KSTR = 40;    // k_attn BT tile stride (bf16)

typedef __attribute__((ext_vector_type(8))) short short8;
typedef __attribute__((ext_vector_type(4))) float f32x4;

// ---------------- dtype detector ----------------
__global__ void k_detect(const void* __restrict__ mask, int* __restrict__ flag){
    if(threadIdx.x==0 && blockIdx.x==0)
        flag[0] = (((const unsigned short*)mask)[0] == 0x3F80) ? 1 : 0;
}

// ---------------- merged small-vector conversion ----------------
#define MAXSEG 32
struct ConvSegs {
    const void* src[MAXSEG];
    int dst_off[MAXSEG];
    int blk0[MAXSEG];
    int total[MAXSEG];
};

__global__ void k_conv_multi(ConvSegs sg, int nseg, float* __restrict__ wsf,
                             const int* __restrict__ dt){
    int isb = dt[0];
    int b = blockIdx.x;
    int s = 0;
    #pragma unroll 1
    while(s+1 < nseg && sg.blk0[s+1] <= b) ++s;
    int idx = (b - sg.blk0[s])*256 + threadIdx.x;
    if(idx >= sg.total[s]) return;
    wsf[(size_t)sg.dst_off[s] + idx] = ldin(sg.src[s], idx, isb);
}

// ---------------- merged weight transpose -> bf16 BT[n][k] ----------------
#define MAXTSEG 12
struct TSegs {
    const void* src[MAXTSEG];
    size_t dst_off[MAXTSEG];
    int N[MAXTSEG];
    int dstK[MAXTSEG];
    int blk0[MAXTSEG];
    int total[MAXTSEG];
};

__global__ void k_transpose_multi(TSegs sg, int nseg, bf16* __restrict__ base,
                                  const int* __restrict__ dt){
    int isb = dt[0];
    int b = blockIdx.x;
    int s = 0;
    #pragma unroll 1
    while(s+1 < nseg && sg.blk0[s+1] <= b) ++s;
    int idx = (b - sg.blk0[s])*256 + threadIdx.x;
    if(idx >= sg.total[s]) return;
    int N = sg.N[s];
    int k = idx / N, n = idx - k*N;
    base[sg.dst_off[s] + (size_t)n*sg.dstK[s] + k] = f2b(ldin(sg.src[s], idx, isb));
}

__global__ void k_wbT(const void* __restrict__ wb, bf16* __restrict__ wbT,
                      const int* __restrict__ dt){
    int isb = dt[0];
    for(int idx=threadIdx.x; idx<16*CZ; idx+=256){
        int nn = idx>>7, kk = idx&127;
        float v = (nn < NH) ? ldin(wb, (size_t)kk*NH+nn, isb) : 0.f;
        wbT[idx] = f2b(v);
    }
}

__global__ void k_init_frames(float* __restrict__ quats, float* __restrict__ trans){
    int i = blockIdx.x*blockDim.x + threadIdx.x;
    if(i < NRES){
        quats[i*4+0]=1.f; quats[i*4+1]=0.f; quats[i*4+2]=0.f; quats[i*4+3]=0.f;
        trans[i*3+0]=0.f; trans[i*3+1]=0.f; trans[i*3+2]=0.f;
    }
}

// LayerNorm (fp32/bf16 dual output).
// nsum>0: in = fp32 partials [nsum][NRES][Cdim]; v = sum(partials) + sbias[c] + sres[row][c].
// do_frames: fused quat/trans update + frames/pos outputs (uses LN'd row = new s).
__global__ __launch_bounds__(128) void k_ln(const void* __restrict__ in, int in_dyn,
                     float* __restrict__ out, bf16* __restrict__ out16,
                     const float* __restrict__ g, const float* __restrict__ b, int Cdim,
                     void* __restrict__ outp, size_t st_ofs, size_t fin_ofs, int mode,
                     const int* __restrict__ dt, int nsum,
                     const float* __restrict__ sbias, const float* __restrict__ sres,
                     int do_frames,
                     const float* __restrict__ wbb_f, const float* __restrict__ bbb_f,
                     const float* __restrict__ rotp, const int* __restrict__ restype,
                     const float* __restrict__ lit_f,
                     float* __restrict__ quats, float* __restrict__ trans,
                     size_t frames_ofs, size_t pos_ofs){
    int row = blockIdx.x, tid = threadIdx.x;
    int isb = dt[0];
    int isb_in = in_dyn ? isb : 0;
    float s=0.f, s2=0.f, vals[3];
    int r=0;
    for(int c=tid; c<Cdim; c+=128, ++r){
        size_t idx = (size_t)row*Cdim + c;
        float v;
        if(nsum > 0){
            const float* pf = (const float*)in;
            v = sbias[c] + sres[idx];
            for(int p=0;p<nsum;p++) v += pf[(size_t)p*NRES*Cdim + idx];
        } else {
            v = ldin(in, idx, isb_in);
        }
        vals[r]=v; s+=v; s2+=v*v;
    }
    __shared__ float red[128], red2[128];
    red[tid]=s; red2[tid]=s2; __syncthreads();
    for(int st=64; st>0; st>>=1){ if(tid<st){ red[tid]+=red[tid+st]; red2[tid]+=red2[tid+st]; } __syncthreads(); }
    float mu = red[0]/Cdim;
    float var = red2[0]/Cdim - mu*mu;
    float rs = rsqrtf(var + 1e-5f);
    float facc[6] = {};
    r=0;
    for(int c=tid; c<Cdim; c+=128, ++r){
        float v = (vals[r]-mu)*rs*g[c] + b[c];
        size_t idx = (size_t)row*Cdim + c;
        if(out)   out[idx] = v;
        if(out16) out16[idx] = f2b(v);
        if(mode >= 1){
            stout(outp, st_ofs + idx, v, isb);
            if(mode == 2) stout(outp, fin_ofs + idx, v, isb);
        }
        if(do_frames){
            #pragma unroll
            for(int j=0;j<6;j++) facc[j] += v * wbb_f[c*6+j];
        }
    }
    if(do_frames){
        int lane = tid&63, wv = tid>>6;
        #pragma unroll
        for(int m=32; m>=1; m>>=1)
            #pragma unroll
            for(int j=0;j<6;j++) facc[j] += __shfl_xor(facc[j], m, 64);
        __shared__ float fred[2][6];
        if(lane==0){
            #pragma unroll
            for(int j=0;j<6;j++) fred[wv][j] = facc[j];
        }
        __syncthreads();
        if(tid==0){
            int i = row;
            float u[6];
            #pragma unroll
            for(int j=0;j<6;j++) u[j] = fred[0][j] + fred[1][j] + bbb_f[j];
            float qw=quats[i*4], qx=quats[i*4+1], qy=quats[i*4+2], qz=quats[i*4+3];
            float nw = qw       - qx*u[0] - qy*u[1] - qz*u[2];
            float nx = qw*u[0] + qx       + qy*u[2] - qz*u[1];
            float ny = qw*u[1] - qx*u[2] + qy       + qz*u[0];
            float nz = qw*u[2] + qx*u[1] - qy*u[0] + qz;
            float rn = rsqrtf(nw*nw + nx*nx + ny*ny + nz*nz);
            nw*=rn; nx*=rn; ny*=rn; nz*=rn;
            quats[i*4]=nw; quats[i*4+1]=nx; quats[i*4+2]=ny; quats[i*4+3]=nz;
            const float* R = rotp + i*9;   // OLD rot (this iteration's)
            float tx = trans[i*3]   + R[0]*u[3]+R[1]*u[4]+R[2]*u[5];
            float ty = trans[i*3+1] + R[3]*u[3]+R[4]*u[4]+R[5]*u[5];
            float tz = trans[i*3+2] + R[6]*u[3]+R[7]*u[4]+R[8]*u[5];
            trans[i*3]=tx; trans[i*3+1]=ty; trans[i*3+2]=tz;
            size_t f = frames_ofs + (size_t)i*7;
            stout(outp, f+0, nw, isb); stout(outp, f+1, nx, isb);
            stout(outp, f+2, ny, isb); stout(outp, f+3, nz, isb);
            stout(outp, f+4, 10.f*tx, isb); stout(outp, f+5, 10.f*ty, isb); stout(outp, f+6, 10.f*tz, isb);
            float Rn[9];
            Rn[0]=nw*nw+nx*nx-ny*ny-nz*nz; Rn[1]=2.f*(nx*ny-nw*nz);       Rn[2]=2.f*(nx*nz+nw*ny);
            Rn[3]=2.f*(nx*ny+nw*nz);       Rn[4]=nw*nw-nx*nx+ny*ny-nz*nz; Rn[5]=2.f*(ny*nz-nw*nx);
            Rn[6]=2.f*(nx*nz-nw*ny);       Rn[7]=2.f*(ny*nz+nw*nx);       Rn[8]=nw*nw-nx*nx-ny*ny+nz*nz;
            int rt = restype[i];
            size_t po = pos_ofs + (size_t)i*9;
            #pragma unroll
            for(int a=0;a<3;a++){
                float lx=lit_f[(rt*3+a)*3+0], ly=lit_f[(rt*3+a)*3+1], lz=lit_f[(rt*3+a)*3+2];
                stout(outp, po+a*3+0, Rn[0]*lx + Rn[1]*ly + Rn[2]*lz + 10.f*tx, isb);
                stout(outp, po+a*3+1, Rn[3]*lx + Rn[4]*ly + Rn[5]*lz + 10.f*ty, isb);
                stout(outp, po+a*3+2, Rn[6]*lx + Rn[7]*ly + Rn[8]*lz + 10.f*tz, isb);
            }
        }
    }
}

// ---------------- bf16 MFMA GEMM ----------------
// lda = row stride of A and BT. blockIdx.z selects K-chunk of length K at z*K;
// Cf indexed by z (fp32 partials).
__global__ __launch_bounds__(256) void k_gemm_bf(const bf16* __restrict__ A,
        const bf16* __restrict__ BT, float* __restrict__ Cf, bf16* __restrict__ C16,
        const float* __restrict__ bias, const float* __restrict__ res,
        int M, int Nn, int K, int relu, int lda){
    __shared__ bf16 As[64*SAK];
    __shared__ bf16 Bs[64*SAK];
    int tid = threadIdx.x;
    int bm = blockIdx.y*64, bn = blockIdx.x*64;
    int kofs = blockIdx.z*K;
    int wave = tid>>6, lane = tid&63;
    int quad = lane>>4, m16 = lane&15;
    int wm = (wave>>1)*32, wn = (wave&1)*32;
    int srow = wave*16 + (lane>>2);
    int scol = (lane&3)*8;
    const bf16* Ag = A  + (size_t)(bm + srow)*lda + kofs + scol;
    const bf16* Bg = BT + (size_t)(bn + srow)*lda + kofs + scol;
    int ldw = srow*SAK + scol;
    f32x4 acc[2][2] = {};
    short8 ra = *(const short8*)Ag;
    short8 rb = *(const short8*)Bg;
    int nsteps = K >> 5;
    const short* Asp = (const short*)As;
    const short* Bsp = (const short*)Bs;
    for(int s=0; s<nsteps; ++s){
        __syncthreads();
        *(short8*)(As + ldw) = ra;
        *(short8*)(Bs + ldw) = rb;
        __syncthreads();
        if(s+1 < nsteps){
            ra = *(const short8*)(Ag + (size_t)(s+1)*32);
            rb = *(const short8*)(Bg + (size_t)(s+1)*32);
        }
        short8 a0 = *(const short8*)&Asp[(wm +      m16)*SAK + quad*8];
        short8 a1 = *(const short8*)&Asp[(wm + 16 + m16)*SAK + quad*8];
        short8 b0 = *(const short8*)&Bsp[(wn +      m16)*SAK + quad*8];
        short8 b1 = *(const short8*)&Bsp[(wn + 16 + m16)*SAK + quad*8];
        acc[0][0] = __builtin_amdgcn_mfma_f32_16x16x32_bf16(a0, b0, acc[0][0], 0,0,0);
        acc[0][1] = __builtin_amdgcn_mfma_f32_16x16x32_bf16(a0, b1, acc[0][1], 0,0,0);
        acc[1][0] = __builtin_amdgcn_mfma_f32_16x16x32_bf16(a1, b0, acc[1][0], 0,0,0);
        acc[1][1] = __builtin_amdgcn_mfma_f32_16x16x32_bf16(a1, b1, acc[1][1], 0,0,0);
    }
    float* Cfz = Cf ? Cf + (size_t)blockIdx.z*M*Nn : nullptr;
    #pragma unroll
    for(int tm=0;tm<2;tm++){
        #pragma unroll
        for(int r=0;r<4;r++){
            int row = bm + wm + tm*16 + quad*4 + r;
            #pragma unroll
            for(int tn=0;tn<2;tn++){
                int col = bn + wn + tn*16 + m16;
                float v = acc[tm][tn][r];
                if(bias) v += bias[col];
                if(res)  v += res[(size_t)row*Nn + col];
                if(relu) v = fmaxf(v, 0.f);
                if(Cfz) Cfz[(size_t)row*Nn + col] = v;
                if(C16) C16[(size_t)row*Nn + col] = f2b(v);
            }
        }
    }
}

// ---------------- zb via MFMA (+ zn16 materialization) ----------------
// v2: 2 tiles/wave (grid 2048), all pair loads issued up-front per path so the
// wave keeps >=2 full load rounds in flight (was: 4 serial load->LN->store tiles).
__global__ __launch_bounds__(256) void k_zb_mfma(const void* __restrict__ pair,
        const float* __restrict__ gz, const float* __restrict__ bz,
        const bf16* __restrict__ wbT, bf16* __restrict__ zb16,
        bf16* __restrict__ zn16, const int* __restrict__ dt){
    int isb = dt[0];
    __shared__ float gs[CZ], bs[CZ];
    int t = threadIdx.x;
    if(t < CZ){ gs[t]=gz[t]; bs[t]=bz[t]; }
    int wave = t>>6, lane = t&63;
    int m = lane&15, quad = lane>>4;
    int r0 = blockIdx.x*128 + wave*32;          // this wave: rows r0 .. r0+31 (2 tiles)
    const short* pps = (const short*)pair;
    const float* ppf = (const float*)pair;

    // B fragments (tiny, L1/L2-hot)
    short8 bfrag[4];
    const short* wbs = (const short*)wbT;
    #pragma unroll
    for(int kc=0;kc<4;kc++) bfrag[kc] = *(const short8*)(wbs + m*CZ + kc*32 + quad*8);

    float vals0[32], vals1[32];
    if(isb){
        short8 pr0[4], pr1[4];
        const short* p0 = pps + (size_t)(r0 +      m)*CZ + quad*8;
        const short* p1 = pps + (size_t)(r0 + 16 + m)*CZ + quad*8;
        #pragma unroll
        for(int kc=0;kc<4;kc++) pr0[kc] = *(const short8*)(p0 + kc*32);
        #pragma unroll
        for(int kc=0;kc<4;kc++) pr1[kc] = *(const short8*)(p1 + kc*32);
        #pragma unroll
        for(int kc=0;kc<4;kc++)
            #pragma unroll
            for(int j=0;j<8;j++){
                vals0[kc*8+j] = b2f(((const bf16*)&pr0[kc])[j]);
                vals1[kc*8+j] = b2f(((const bf16*)&pr1[kc])[j]);
            }
    } else {
        const float* p0 = ppf + (size_t)(r0 +      m)*CZ + quad*8;
        const float* p1 = ppf + (size_t)(r0 + 16 + m)*CZ + quad*8;
        #pragma unroll
        for(int kc=0;kc<4;kc++){
            *(float4*)&vals0[kc*8]   = *(const float4*)(p0 + kc*32);
            *(float4*)&vals0[kc*8+4] = *(const float4*)(p0 + kc*32 + 4);
            *(float4*)&vals1[kc*8]   = *(const float4*)(p1 + kc*32);
            *(float4*)&vals1[kc*8+4] = *(const float4*)(p1 + kc*32 + 4);
        }
    }
    __syncthreads();   // gs/bs ready (also drains the loads above, all in flight together)

    #pragma unroll
    for(int tile=0; tile<2; ++tile){
        const float* vals = tile ? vals1 : vals0;
        int rowbase = r0 + tile*16;
        int row = rowbase + m;
        float s=0.f, s2=0.f;
        #pragma unroll
        for(int j=0;j<32;j++){ float v=vals[j]; s+=v; s2+=v*v; }
        s  += __shfl_xor(s,16,64);  s  += __shfl_xor(s,32,64);
        s2 += __shfl_xor(s2,16,64); s2 += __shfl_xor(s2,32,64);
        float mu = s*(1.f/CZ);
        float var = s2*(1.f/CZ) - mu*mu;
        float rsd = rsqrtf(var + 1e-5f);
        f32x4 acc = {0.f,0.f,0.f,0.f};
        #pragma unroll
        for(int kc=0;kc<4;kc++){
            int c0 = kc*32 + quad*8;
            short8 a;
            #pragma unroll
            for(int j=0;j<8;j++){
                float zn = (vals[kc*8+j]-mu)*rsd*gs[c0+j] + bs[c0+j];
                ((bf16*)&a)[j] = f2b(zn);
            }
            *(short8*)((short*)zn16 + (size_t)row*CZ + c0) = a;
            acc = __builtin_amdgcn_mfma_f32_16x16x32_bf16(a, bfrag[kc], acc, 0, 0, 0);
        }
        if(m < NH){
            unsigned short pk[4];
            #pragma unroll
            for(int r=0;r<4;r++){ bf16 h = f2b(acc[r]); pk[r] = *(unsigned short*)&h; }
            size_t o = (size_t)m*((size_t)NRES*NRES) + (size_t)(rowbase + quad*4);
            *(uint2*)((unsigned short*)zb16 + o) = *(const uint2*)pk;
        }
    }
}

// ---------------- per-iteration kernels ----------------

// Sums proj split-K partials + bias into LDS, then scatters.
__global__ __launch_bounds__(192) void k_rotate_kv(const float* __restrict__ qpw,
        const float* __restrict__ bproj,
        const float* __restrict__ quats, const float* __restrict__ trans,
        float* __restrict__ rot,
        float* __restrict__ qp_rot, float* __restrict__ kp_rot, bf16* __restrict__ vp16,
        float* __restrict__ k_buf, bf16* __restrict__ v16, float* __restrict__ q_buf){
    int i = blockIdx.x, t = threadIdx.x;
    __shared__ float R[9], T[3];
    __shared__ float rowbuf[1152];
    const float* q0 = qpw + (size_t)i*1152;
    const float* q1 = qpw + (size_t)NRES*1152 + (size_t)i*1152;
    #pragma unroll
    for(int r=0;r<6;r++){
        int c = t + 192*r;
        rowbuf[c] = q0[c] + q1[c] + bproj[c];
    }
    if(t==0){
        float w=quats[i*4],x=quats[i*4+1],y=quats[i*4+2],z=quats[i*4+3];
        R[0]=w*w+x*x-y*y-z*z; R[1]=2.f*(x*y-w*z);     R[2]=2.f*(x*z+w*y);
        R[3]=2.f*(x*y+w*z);   R[4]=w*w-x*x+y*y-z*z;   R[5]=2.f*(y*z-w*x);
        R[6]=2.f*(x*z-w*y);   R[7]=2.f*(y*z+w*x);     R[8]=w*w-x*x-y*y+z*z;
    }
    if(t<3) T[t] = trans[i*3+t];
    __syncthreads();
    if(t<9) rot[i*9+t] = R[t];
    q_buf[(size_t)i*192 + t] = rowbuf[t];
    {
        int h = t/16, c = t%16;
        k_buf[((size_t)h*NRES + i)*16 + c] = rowbuf[192 + h*32 + c];
        v16[(size_t)i*192 + t]             = f2b(rowbuf[192 + h*32 + 16 + c]);
    }
    if(t < 48){
        float vx = rowbuf[576 + t], vy = rowbuf[576 + 48 + t], vz = rowbuf[576 + 96 + t];
        float* o = qp_rot + ((size_t)i*48 + t)*3;
        o[0] = R[0]*vx + R[1]*vy + R[2]*vz + T[0];
        o[1] = R[3]*vx + R[4]*vy + R[5]*vz + T[1];
        o[2] = R[6]*vx + R[7]*vy + R[8]*vz + T[2];
    }
    if(t < 144){
        int hp = t;
        float vx = rowbuf[720 + hp], vy = rowbuf[720 + 144 + hp], vz = rowbuf[720 + 288 + hp];
        float ox = R[0]*vx + R[1]*vy + R[2]*vz + T[0];
        float oy = R[3]*vx + R[4]*vy + R[5]*vz + T[1];
        float oz = R[6]*vx + R[7]*vy + R[8]*vz + T[2];
        int h = hp/12, p = hp%12;
        if(p < PQn){
            float* o = kp_rot + ((size_t)i*48 + h*4 + p)*3;
            o[0]=ox; o[1]=oy; o[2]=oz;
        } else {
            bf16* o = vp16 + ((size_t)i*96 + h*8 + (p-4))*3;
            o[0]=f2b(ox); o[1]=f2b(oy); o[2]=f2b(oz);
        }
    }
}

// attention logits + softmax via MFMA.
__global__ __launch_bounds__(256) void k_attn(const float* __restrict__ q_buf,
        const float* __restrict__ k_buf, const float* __restrict__ qp_rot,
        const float* __restrict__ kp_rot, const bf16* __restrict__ zb16,
        const float* __restrict__ hw_f, const float* __restrict__ bbz_f,
        const void* __restrict__ mask, bf16* __restrict__ a16,
        const int* __restrict__ dt){
    int i0 = blockIdx.x*16, h = blockIdx.y;
    int t = threadIdx.x;
    int isb = dt[0];
    __shared__ bf16 kb_s[NRES*KSTR];
    __shared__ bf16 zb_s[16*NRES];
    __shared__ bf16 as_s[16*KSTR];
    __shared__ float colc_s[NRES];
    __shared__ float mcol_s[NRES];
    __shared__ float rowc_s[16], mrow_s[16];
    __shared__ float redm[4][16], reds[4][16];
    float hwx = hw_f[h];
    float sp = (hwx > 20.f) ? hwx : log1pf(expf(hwx));
    float hw = sp * 0.13608276348795434f;             // softplus(w) * sqrt(1/54)
    float zbb = 0.57735026919f * bbz_f[h];
    #pragma unroll
    for(int rr=0; rr<2; ++rr){
        int j = t*2 + rr;
        const float* kr  = k_buf  + ((size_t)h*NRES + j)*16;
        const float* kpr = kp_rot + ((size_t)j*48 + h*4)*3;
        bf16* dstp = kb_s + j*KSTR;
        float kv[16], pv[12];
        *(float4*)&kv[0]  = *(const float4*)(kr);       // vectorized staging (was 16 scalar loads)
        *(float4*)&kv[4]  = *(const float4*)(kr + 4);
        *(float4*)&kv[8]  = *(const float4*)(kr + 8);
        *(float4*)&kv[12] = *(const float4*)(kr + 12);
        *(float4*)&pv[0]  = *(const float4*)(kpr);      // (j*144 + h*12) floats -> 16B aligned
        *(float4*)&pv[4]  = *(const float4*)(kpr + 4);
        *(float4*)&pv[8]  = *(const float4*)(kpr + 8);
        #pragma unroll
        for(int c=0;c<16;c++) dstp[c] = f2b(kv[c]);
        float s2k = 0.f;
        #pragma unroll
        for(int p=0;p<12;p++){ float v = pv[p]; s2k += v*v; dstp[16+p] = f2b(v); }
        dstp[28]=f2b(0.f); dstp[29]=f2b(0.f); dstp[30]=f2b(0.f); dstp[31]=f2b(0.f);
        colc_s[j] = -0.5f*hw*s2k;
        mcol_s[j] = ldin(mask, j, isb);
    }
    {
        const short8* zsrc = (const short8*)((const unsigned short*)zb16 + (size_t)h*NRES*NRES + (size_t)i0*NRES);
        short8* zdst = (short8*)zb_s;
        #pragma unroll
        for(int r=0;r<4;r++) zdst[t + r*256] = zsrc[t + r*256];
    }
    if(t < 16){
        int m = t;
        const float* qr = q_buf + (size_t)(i0+m)*192 + h*16;
        bf16* dstp = as_s + m*KSTR;
        float qv[16], qpv[12];
        *(float4*)&qv[0]  = *(const float4*)(qr);
        *(float4*)&qv[4]  = *(const float4*)(qr + 4);
        *(float4*)&qv[8]  = *(const float4*)(qr + 8);
        *(float4*)&qv[12] = *(const float4*)(qr + 12);
        const float* qpr = qp_rot + ((size_t)(i0+m)*48 + h*4)*3;
        *(float4*)&qpv[0] = *(const float4*)(qpr);
        *(float4*)&qpv[4] = *(const float4*)(qpr + 4);
        *(float4*)&qpv[8] = *(const float4*)(qpr + 8);
        #pragma unroll
        for(int c=0;c<16;c++) dstp[c] = f2b(qv[c]*0.14433756729740643f);   // sqrt(1/48)
        float s2q = 0.f;
        #pragma unroll
        for(int p=0;p<12;p++){ float v = qpv[p]; s2q += v*v; dstp[16+p] = f2b(v*hw); }
        dstp[28]=f2b(0.f); dstp[29]=f2b(0.f); dstp[30]=f2b(0.f); dstp[31]=f2b(0.f);
        rowc_s[m] = -0.5f*hw*s2q;
        mrow_s[m] = ldin(mask, i0+m, isb);
    }
    __syncthreads();
    int lane = t&63, wv = t>>6;
    int quad = lane>>4, m16 = lane&15;
    short8 afrag = *(const short8*)((const short*)as_s + m16*KSTR + quad*8);
    float l[8][4];
    #pragma unroll
    for(int tt=0; tt<8; ++tt){
        int jt = wv*8 + tt;
        short8 bfrag = *(const short8*)((const short*)kb_s + (jt*16+m16)*KSTR + quad*8);
        f32x4 acc = {0.f,0.f,0.f,0.f};
        acc = __builtin_amdgcn_mfma_f32_16x16x32_bf16(afrag, bfrag, acc, 0,0,0);
        int j = jt*16 + m16;
        float cc = colc_s[j] + zbb;
        float mj = mcol_s[j];
        #pragma unroll
        for(int r=0;r<4;r++){
            int row = quad*4 + r;
            float zbv = b2f(zb_s[row*NRES + j]);
            l[tt][r] = acc[r] + 0.57735026919f*zbv + cc + rowc_s[row]
                     + 100000.0f*(mrow_s[row]*mj - 1.0f);
        }
    }
    float lm[4], ls[4];
    #pragma unroll
    for(int r=0;r<4;r++){
        float m = l[0][r];
        #pragma unroll
        for(int tt=1;tt<8;tt++) m = fmaxf(m, l[tt][r]);
        #pragma unroll
        for(int msk=1; msk<16; msk<<=1) m = fmaxf(m, __shfl_xor(m, msk, 64));
        lm[r] = m;
        float s = 0.f;
        #pragma unroll
        for(int tt=0;tt<8;tt++){ float e = expf(l[tt][r]-m); l[tt][r] = e; s += e; }
        #pragma unroll
        for(int msk=1; msk<16; msk<<=1) s += __shfl_xor(s, msk, 64);
        ls[r] = s;
    }
    if(m16 == 0){
        #pragma unroll
        for(int r=0;r<4;r++){ redm[wv][quad*4+r] = lm[r]; reds[wv][quad*4+r] = ls[r]; }
    }
    __syncthreads();
    #pragma unroll
    for(int r=0;r<4;r++){
        int row = quad*4+r;
        float M = redm[0][row];
        #pragma unroll
        for(int w=1;w<4;w++) M = fmaxf(M, redm[w][row]);
        float S = 0.f;
        #pragma unroll
        for(int w=0;w<4;w++) S += reds[w][row]*expf(redm[w][row]-M);
        float f = expf(lm[r]-M)/S;
        #pragma unroll
        for(int tt=0;tt<8;tt++){
            int j = (wv*8+tt)*16 + m16;
            a16[((size_t)h*NRES + i0+row)*NRES + j] = f2b(l[tt][r]*f);
        }
    }
}

// fused a@[v | vp | zn] + opt rotate-back.
__global__ __launch_bounds__(512) void k_attn_out(const bf16* __restrict__ a16,
        const bf16* __restrict__ v16, const bf16* __restrict__ vp16,
        const bf16* __restrict__ zn16,
        const float* __restrict__ rot, const float* __restrict__ trans,
        bf16* __restrict__ o_cat16){
    int i = blockIdx.x, t = threadIdx.x;
    __shared__ float a_sf[NH*ASTR];
    __shared__ bf16  zn_s[32*ZSTR];
    __shared__ float opt_s[288];
    for(int idx=t; idx<NH*NRES; idx+=512){
        int h = idx>>9, j = idx&511;
        a_sf[h*ASTR + j] = b2f(a16[((size_t)h*NRES + i)*NRES + j]);
    }
    int lane = t&63, quad = lane>>4, m16 = lane&15;
    int wv = t>>6;
    int jj = t>>4, c8 = (t&15)*8;
    int pc = t;
    int h0 = (pc<192) ? (pc>>4) : (pc-192)/24;
    const bf16* s0 = (pc<192) ? (v16 + pc) : (vp16 + (pc-192));
    int st0 = (pc<192) ? 192 : 288;
    const bf16* s1 = vp16 + 192 + t;
    int h1 = (192 + t)/24;               // heads 8..11
    float acc0 = 0.f, acc1 = 0.f;
    f32x4 macc[4] = {};
    __syncthreads();
    for(int j0=0; j0<NRES; j0+=32){
        if(j0) __syncthreads();
        {
            size_t pb = ((size_t)i*NRES + j0+jj)*CZ + c8;
            short8 z8 = *(const short8*)((const short*)zn16 + pb);
            *(short8*)&zn_s[jj*ZSTR + c8] = z8;
        }
        __syncthreads();
        if(wv < 6){
            const float* ap0 = a_sf + h0*ASTR;
            #pragma unroll
            for(int u=0; u<32; u+=4){
                int j = j0+u;
                float4 a4 = *(const float4*)(ap0 + j);
                acc0 += a4.x*b2f(s0[(size_t)j*st0])     + a4.y*b2f(s0[(size_t)(j+1)*st0])
                      + a4.z*b2f(s0[(size_t)(j+2)*st0]) + a4.w*b2f(s0[(size_t)(j+3)*st0]);
            }
            if(t < 96){
                const float* ap1 = a_sf + h1*ASTR;
                #pragma unroll
                for(int u=0; u<32; u+=4){
                    int j = j0+u;
                    float4 a4 = *(const float4*)(ap1 + j);
                    acc1 += a4.x*b2f(s1[(size_t)j*288])     + a4.y*b2f(s1[(size_t)(j+1)*288])
                          + a4.z*b2f(s1[(size_t)(j+2)*288]) + a4.w*b2f(s1[(size_t)(j+3)*288]);
                }
            }
        } else {
            float4 af0 = *(const float4*)&a_sf[m16*ASTR + j0 + quad*8];
            float4 af1 = *(const float4*)&a_sf[m16*ASTR + j0 + quad*8 + 4];
            short8 afrag;
            float az[8] = {af0.x,af0.y,af0.z,af0.w,af1.x,af1.y,af1.z,af1.w};
            #pragma unroll
            for(int r=0;r<8;r++) ((bf16*)&afrag)[r] = f2b((m16 < NH) ? az[r] : 0.f);
            int cbase = (wv-6)*64;
            #pragma unroll
            for(int tn=0; tn<4; ++tn){
                int c0 = cbase + tn*16;
                short8 bfrag;
                #pragma unroll
                for(int r=0;r<8;r++) ((bf16*)&bfrag)[r] = zn_s[(quad*8+r)*ZSTR + c0 + m16];
                macc[tn] = __builtin_amdgcn_mfma_f32_16x16x32_bf16(afrag, bfrag, macc[tn], 0,0,0);
            }
        }
    }
    if(wv >= 6){
        int cbase = (wv-6)*64;
        #pragma unroll
        for(int tn=0; tn<4; ++tn){
            int c = cbase + tn*16 + m16;
            #pragma unroll
            for(int r=0;r<4;r++){
                int h = quad*4 + r;
                if(h < NH) o_cat16[(size_t)i*CAT + 576 + h*CZ + c] = f2b(macc[tn][r]);
            }
        }
    } else {
        if(pc < 192) o_cat16[(size_t)i*CAT + pc] = f2b(acc0);
        else         opt_s[pc-192] = acc0;
        if(t < 96)   opt_s[192+t] = acc1;
    }
    __syncthreads();
    if(t < 96){
        float R0=rot[i*9+0],R1=rot[i*9+1],R2=rot[i*9+2];
        float R3=rot[i*9+3],R4=rot[i*9+4],R5=rot[i*9+5];
        float R6=rot[i*9+6],R7=rot[i*9+7],R8=rot[i*9+8];
        float T0=trans[i*3+0],T1=trans[i*3+1],T2=trans[i*3+2];
        const float* v = opt_s + t*3;
        float vx=v[0]-T0, vy=v[1]-T1, vz=v[2]-T2;
        float ox = R0*vx + R3*vy + R6*vz;
        float oy = R1*vx + R4*vy + R7*vz;
        float oz = R2*vx + R5*vy + R8*vz;
        bf16* o = o_cat16 + (size_t)i*CAT;
        o[192 +       t] = f2b(ox);
        o[192 +  96 + t] = f2b(oy);
        o[192 + 192 + t] = f2b(oz);
        o[480 + t] = f2b(sqrtf(ox*ox + oy*oy + oz*oz + 1e-8f));
    }
}

// ---------------- launch ----------------

extern "C" void kernel_launch(void* const* d_in, const int* in_sizes, int n_in,
                              void* d_out, int out_size, void* d_ws, size_t ws_size,
                              hipStream_t stream){
    (void)in_sizes; (void)n_in; (void)out_size; (void)ws_size;
    const void* single = d_in[0];
    const void* pair   = d_in[1];
    const int*  restype= (const int*)d_in[2];
    const void* mask   = d_in[3];

    float* wsf = (float*)d_ws;
    bf16*  wsb = (bf16*)d_ws;
    size_t off = 0;
    auto alloc  = [&](size_t n){ float* p = wsf + off; off += (n + 3) & ~(size_t)3; return p; };
    auto allocB = [&](size_t n){ bf16* p = (bf16*)(wsf + off); off += ((n+1)/2 + 3) & ~(size_t)3; return p; };
    int*   dflag  = (int*)alloc(4);
    float* s      = alloc((size_t)NRES*CS);
    float* stmp   = alloc((size_t)NRES*CS);
    float* pw     = alloc((size_t)3*NRES*CS);       // wo / t3 K-split partials
    float* qpw    = alloc((size_t)2*NRES*1152);     // proj K-split partials
    float* q_buf  = alloc((size_t)NRES*192);
    float* qp_rot = alloc((size_t)NRES*144);
    float* kp_rot = alloc((size_t)NRES*144);
    float* k_bufp = alloc((size_t)NH*NRES*16);
    float* quats  = alloc(NRES*4);
    float* trans  = alloc(NRES*3);
    float* rot    = alloc(NRES*9);
    bf16*  a16    = allocB((size_t)NH*NRES*NRES);
    bf16*  zb16   = allocB((size_t)NH*NRES*NRES);
    bf16*  zn16   = allocB((size_t)NRES*NRES*CZ);
    bf16*  v16    = allocB((size_t)NRES*192);
    bf16*  vp16   = allocB((size_t)NRES*288);
    bf16*  o_cat16= allocB((size_t)NRES*CAT);
    bf16*  sin16  = allocB((size_t)NRES*CS);
    bf16*  s16    = allocB((size_t)NRES*CS);
    bf16*  t116   = allocB((size_t)NRES*CS);
    bf16*  t216   = allocB((size_t)NRES*CS);
    bf16*  WprojT = allocB((size_t)1152*CS);
    bf16*  w_inT  = allocB((size_t)CS*CS);
    bf16*  woT    = allocB((size_t)CS*CAT);
    bf16*  tw1T   = allocB((size_t)CS*CS);
    bf16*  tw2T   = allocB((size_t)CS*CS);
    bf16*  tw3T   = allocB((size_t)CS*CS);
    bf16*  wbT    = allocB(16*CZ);
    float* b_in_f = alloc(CS);
    float* bproj  = alloc(1152);
    float* bo_f   = alloc(CS);
    float* tb1f   = alloc(CS);
    float* tb2f   = alloc(CS);
    float* tb3f   = alloc(CS);
    float* lnsg   = alloc(CS);
    float* lnsb   = alloc(CS);
    float* lnig   = alloc(CS);
    float* lnib   = alloc(CS);
    float* lntg   = alloc(CS);
    float* lntb   = alloc(CS);
    float* gz_f   = alloc(CZ);
    float* bz_f   = alloc(CZ);
    float* bbz_f  = alloc(16);
    float* hw_f   = alloc(16);
    float* wbb_f  = alloc(CS*6);
    float* bbb_f  = alloc(8);
    float* lit_f  = alloc(48);

    const size_t OF_FRAMES = 0;
    const size_t OF_POS    = 28672;
    const size_t OF_STATES = 65536;
    const size_t OF_FINAL  = 1638400;

    auto cdiv = [](int a, int b){ return (a+b-1)/b; };

    k_detect<<<1,64,0,stream>>>(mask, dflag);

    ConvSegs sg;
    int nseg = 0, blk = 0;
    auto plain = [&](const void* src, float* dst, int total){
        sg.src[nseg]=src; sg.dst_off[nseg]=(int)(dst - wsf);
        sg.total[nseg]=total; sg.blk0[nseg]=blk;
        blk += (total+255)/256; ++nseg;
    };
    plain(d_in[11], bproj,     192);
    plain(d_in[13], bproj+192, 384);
    plain(d_in[15], bproj+576, 144);
    plain(d_in[17], bproj+720, 432);
    plain(d_in[9],  b_in_f, CS);
    plain(d_in[22], bo_f,   CS);
    plain(d_in[26], tb1f,   CS);
    plain(d_in[28], tb2f,   CS);
    plain(d_in[30], tb3f,   CS);
    plain(d_in[4],  lnsg,   CS);
    plain(d_in[5],  lnsb,   CS);
    plain(d_in[23], lnig,   CS);
    plain(d_in[24], lnib,   CS);
    plain(d_in[31], lntg,   CS);
    plain(d_in[32], lntb,   CS);
    plain(d_in[6],  gz_f,   CZ);
    plain(d_in[7],  bz_f,   CZ);
    plain(d_in[19], bbz_f,  NH);
    plain(d_in[20], hw_f,   NH);
    plain(d_in[34], bbb_f,  6);
    plain(d_in[35], lit_f,  45);
    plain(d_in[33], wbb_f,  CS*6);
    k_conv_multi<<<blk,256,0,stream>>>(sg, nseg, wsf, dflag);

    TSegs tg;
    int ntseg = 0, tblk = 0;
    auto trs = [&](const void* src, int K, int N, bf16* dst, int rowofs, int dstK){
        tg.src[ntseg]=src;
        tg.dst_off[ntseg]=(size_t)(dst - wsb) + (size_t)rowofs*dstK;
        tg.N[ntseg]=N; tg.dstK[ntseg]=dstK;
        tg.total[ntseg]=K*N; tg.blk0[ntseg]=tblk;
        tblk += (K*N+255)/256; ++ntseg;
    };
    trs(d_in[10], CS, 192, WprojT, 0,   CS);
    trs(d_in[12], CS, 384, WprojT, 192, CS);
    trs(d_in[14], CS, 144, WprojT, 576, CS);
    trs(d_in[16], CS, 432, WprojT, 720, CS);
    trs(d_in[8],  CS, CS,  w_inT,  0,   CS);
    trs(d_in[21], CAT, CS, woT,    0,   CAT);
    trs(d_in[25], CS, CS,  tw1T,   0,   CS);
    trs(d_in[27], CS, CS,  tw2T,   0,   CS);
    trs(d_in[29], CS, CS,  tw3T,   0,   CS);
    k_transpose_multi<<<tblk,256,0,stream>>>(tg, ntseg, wsb, dflag);
    k_wbT<<<1,256,0,stream>>>(d_in[18], wbT, dflag);

    k_zb_mfma<<<NRES*NRES/128,256,0,stream>>>(pair, gz_f, bz_f, wbT, zb16, zn16, dflag);

    k_ln<<<NRES,128,0,stream>>>(single, 1, nullptr, sin16, lnsg, lnsb, CS, nullptr, 0, 0, 0,
                                dflag, 0, nullptr, nullptr,
                                0, nullptr, nullptr, nullptr, nullptr, nullptr,
                                nullptr, nullptr, 0, 0);
    {
        dim3 g(CS/64, NRES/64);
        k_gemm_bf<<<g,256,0,stream>>>(sin16, w_inT, s, s16, b_in_f, nullptr, NRES, CS, CS, 0, CS);
    }
    k_init_frames<<<cdiv(NRES,256),256,0,stream>>>(quats, trans);

    for(int bi=0; bi<8; ++bi){
        {
            // proj GEMM: K-split 2x192 -> fp32 partials; rotate_kv sums + bias
            dim3 gp(1152/64, NRES/64, 2);
            k_gemm_bf<<<gp,256,0,stream>>>(s16, WprojT, qpw, nullptr, nullptr, nullptr,
                                           NRES, 1152, 192, 0, CS);
        }
        k_rotate_kv<<<NRES,192,0,stream>>>(qpw, bproj, quats, trans, rot, qp_rot, kp_rot,
                                           vp16, k_bufp, v16, q_buf);
        {
            dim3 g(NRES/16, NH);
            k_attn<<<g,256,0,stream>>>(q_buf, k_bufp, qp_rot, kp_rot, zb16, hw_f, bbz_f, mask, a16, dflag);
        }
        k_attn_out<<<NRES,512,0,stream>>>(a16, v16, vp16, zn16, rot, trans, o_cat16);
        {
            // wo GEMM: K-split 3x704 -> fp32 partials; k_ln sums + bias + residual + LN
            dim3 gw(CS/64, NRES/64, 3);
            k_gemm_bf<<<gw,256,0,stream>>>(o_cat16, woT, pw, nullptr, nullptr, nullptr,
                                           NRES, CS, 704, 0, CAT);
            k_ln<<<NRES,128,0,stream>>>(pw, 0, s, s16, lnig, lnib, CS, nullptr, 0, 0, 0,
                                        dflag, 3, bo_f, s,
                                        0, nullptr, nullptr, nullptr, nullptr, nullptr,
                                        nullptr, nullptr, 0, 0);
            dim3 g(CS/64, NRES/64);
            k_gemm_bf<<<g,256,0,stream>>>(s16,  tw1T, nullptr, t116, tb1f, nullptr, NRES, CS, CS, 1, CS);
            k_gemm_bf<<<g,256,0,stream>>>(t116, tw2T, nullptr, t216, tb2f, nullptr, NRES, CS, CS, 1, CS);
            // t3: K-split 2x192 -> partials; final k_ln sums + bias + residual + LN + frames
            dim3 g3(CS/64, NRES/64, 2);
            k_gemm_bf<<<g3,256,0,stream>>>(t216, tw3T, pw, nullptr, nullptr, nullptr,
                                           NRES, CS, 192, 0, CS);
            k_ln<<<NRES,128,0,stream>>>(pw, 0, s, s16, lntg, lntb, CS, d_out,
                                        OF_STATES + (size_t)bi*NRES*CS, OF_FINAL,
                                        (bi==7) ? 2 : 1, dflag, 2, tb3f, s,
                                        1, wbb_f, bbb_f, rot, restype, lit_f,
                                        quats, trans,
                                        OF_FRAMES + (size_t)bi*NRES*7,
                                        OF_POS + (size_t)bi*NRES*9);
        }
    }
}